// Round 10
// baseline (217.819 us; speedup 1.0000x reference)
//
#include <hip/hip_runtime.h>

#define NQ   14
#define DIM  16384      // 2^14
#define BLK  1024
#define WMUL 0.6324555320336759f  // sqrt(2/5)

typedef float v2f __attribute__((ext_vector_type(2)));

struct C2 { float x, y; };  // build-time only
__device__ inline C2 cmulc(C2 a, C2 b){ return C2{a.x*b.x - a.y*b.y, a.x*b.y + a.y*b.x}; }
__device__ inline C2 caddc(C2 a, C2 b){ return C2{a.x+b.x, a.y+b.y}; }
__device__ inline void mm2(const C2* a, const C2* b, C2* o) {
    o[0] = caddc(cmulc(a[0],b[0]), cmulc(a[1],b[2]));
    o[1] = caddc(cmulc(a[0],b[1]), cmulc(a[1],b[3]));
    o[2] = caddc(cmulc(a[2],b[0]), cmulc(a[3],b[2]));
    o[3] = caddc(cmulc(a[2],b[1]), cmulc(a[3],b[3]));
}
__device__ inline void build_gate(int ty, float t, C2* g) {
    float sn, cs;
    __sincosf(0.5f * t, &sn, &cs);
    if (ty == 0) {        // rx
        g[0] = C2{cs, 0.f}; g[1] = C2{0.f, -sn};
        g[2] = C2{0.f, -sn}; g[3] = C2{cs, 0.f};
    } else if (ty == 1) { // ry
        g[0] = C2{cs, 0.f}; g[1] = C2{-sn, 0.f};
        g[2] = C2{sn, 0.f}; g[3] = C2{cs, 0.f};
    } else {              // rz
        g[0] = C2{cs, -sn}; g[1] = C2{0.f, 0.f};
        g[2] = C2{0.f, 0.f}; g[3] = C2{cs, sn};
    }
}
__device__ const int TYPES[5][3] = {
    {0,1,2},  // XYZ
    {1,2,1},  // YZY
    {2,1,0},  // ZYX
    {0,2,0},  // XZX
    {1,2,1},  // YZY
};

// GF(2)-linear bank swizzle: b4..b7 -> s0..s3, b8..b11 -> s0..s3, b12->s2, b13->s3.
// Rank-4 lane->bank map for all three pass configs (A0/M/B).
__device__ __forceinline__ constexpr uint32_t slotf2(uint32_t i){
    return i ^ ((((i>>4) ^ (i>>8) ^ ((i>>12)<<2)) & 15u));
}

// cross-lane xor exchange of a v2f; masks <32 via ds_swizzle (BitMode), 32 via shfl
template<int M>
__device__ __forceinline__ v2f shflx(v2f x){
    if constexpr (M < 32) {
        constexpr int pat = 0x1F | (M << 10);   // and=0x1F, or=0, xor=M
        int a = __builtin_amdgcn_ds_swizzle(__float_as_int(x.x), pat);
        int b = __builtin_amdgcn_ds_swizzle(__float_as_int(x.y), pat);
        return v2f{__int_as_float(a), __int_as_float(b)};
    } else {
        return v2f{__shfl_xor(x.x, 32, 64), __shfl_xor(x.y, 32, 64)};
    }
}

// packed rotation on REG bit J. g = 8 v2f: {mxx,msw} per coeff (00,01,10,11),
// mxx=(m.x,m.x), msw=(-m.y,m.y): cmul(m,a) = mxx*a + msw*a.yx
template<int J>
__device__ __forceinline__ void rot8(v2f* v, const v2f* __restrict__ g){
    const v2f a00=g[0], b00=g[1], a01=g[2], b01=g[3];
    const v2f a10=g[4], b10=g[5], a11=g[6], b11=g[7];
    #pragma unroll
    for (int r = 0; r < 8; ++r){
        if (!(r & (1 << J))) {
            v2f x0 = v[r], x1 = v[r | (1 << J)];
            v2f s0 = x0.yx, s1 = x1.yx;
            v2f y0 = a00*x0 + b00*s0 + a01*x1 + b01*s1;
            v2f y1 = a10*x0 + b10*s0 + a11*x1 + b11*s1;
            v[r] = y0; v[r | (1<<J)] = y1;
        }
    }
}

// packed rotation on LANE bit (xor mask LM): partner via shflx, per-lane row select
template<int LM>
__device__ __forceinline__ void rotL(v2f* v, const v2f* __restrict__ g, uint32_t lane){
    const bool hi = (lane & LM) != 0;
    const v2f c1 = hi ? g[6] : g[0];   // a_ss
    const v2f c2 = hi ? g[7] : g[1];   // b_ss
    const v2f c3 = hi ? g[4] : g[2];   // a_s,other
    const v2f c4 = hi ? g[5] : g[3];   // b_s,other
    #pragma unroll
    for (int r = 0; r < 8; ++r){
        v2f x  = v[r];
        v2f xp = shflx<LM>(x);
        v[r] = c1*x + c2*x.yx + c3*xp + c4*xp.yx;
    }
}

// CNOT variants (ctl/tgt in reg or lane space)
template<int C, int T>
__device__ __forceinline__ void cnotRR(v2f* v){
    #pragma unroll
    for (int r = 0; r < 8; ++r)
        if ((r & (1<<C)) && !(r & (1<<T))) {
            v2f t = v[r]; v[r] = v[r|(1<<T)]; v[r|(1<<T)] = t;
        }
}
template<int C, int TM>
__device__ __forceinline__ void cnotRL(v2f* v){
    #pragma unroll
    for (int r = 0; r < 8; ++r)
        if (r & (1<<C)) v[r] = shflx<TM>(v[r]);
}
template<int CM, int TM>
__device__ __forceinline__ void cnotLL(v2f* v, uint32_t lane){
    const bool c = (lane & CM) != 0;
    #pragma unroll
    for (int r = 0; r < 8; ++r){
        v2f p = shflx<TM>(v[r]);
        v[r] = c ? p : v[r];
    }
}

// ---------------------------------------------------------------------------
// Bit layouts (global amp index bit b, qubit q <-> bit 13-q):
//  A0 (P0):  r0..r2 <-> b11,b12,b13 ; lane l0..l5 <-> b0..b5 ; wave b6..b9, slab b10
//  M:        r0..r2 <-> b9,b10,b11  ; lane l0..l5 <-> b3..b8 ; wave b0..b2,b12, slab b13
//  B:        r0..r2 <-> b2,b3,b4    ; lane l0,l1,l2,l3,l4,l5 <-> b0,b1,b5,b11,b12,b13
//            wave b6..b9, slab b10
// Schedule (10 passes): P0(A0): rot0 q0-2(reg)+q8-13(lane) + CN(0,1),(1,2)
//  M(li):  rot q3,q4(reg)+q5,q6,q7(lane) + CN(2,3)..(8,9)
//  B(li):  CN(9,10)..(13,0) + rot_{li+1} q9-11(reg)+q12,q13,q0,q1,q2,q8(lane)
//          [+ CN_{li+1}(0,1),(1,2) when li+1 has a ring]
//  P9(M):  rot4 q3..q7 + fused <Z_0> (sign = b13 = slab)
// ---------------------------------------------------------------------------

__global__ __launch_bounds__(BLK) void qsim_kernel(
        const float* __restrict__ xr, const float* __restrict__ xi,
        const float* __restrict__ w, float* __restrict__ out) {
    __shared__ v2f s[DIM];            // 128 KiB statevector (slotf2-swizzled)
    __shared__ v2f gmp[5 * NQ * 8];   // 70 gates, packed form (4.4 KiB)
    __shared__ float red[BLK / 64];

    const int b   = blockIdx.x;
    const uint32_t tid  = threadIdx.x;
    const uint32_t lane = tid & 63u;

    // ---- build fused gate matrices (threads 0..69), packed form ----
    if (tid < 5 * NQ) {
        const int li = tid / NQ, q = tid % NQ;
        C2 M[4], G[4], T[4];
        #pragma unroll
        for (int j = 0; j < 3; ++j) {
            float t = w[3 * NQ * li + 3 * q + j] * WMUL;
            build_gate(TYPES[li][j], t, G);
            if (j == 0) { M[0]=G[0]; M[1]=G[1]; M[2]=G[2]; M[3]=G[3]; }
            else { mm2(G, M, T); M[0]=T[0]; M[1]=T[1]; M[2]=T[2]; M[3]=T[3]; }
        }
        #pragma unroll
        for (int k = 0; k < 4; ++k) {
            gmp[tid * 8 + k * 2 + 0] = v2f{ M[k].x, M[k].x};
            gmp[tid * 8 + k * 2 + 1] = v2f{-M[k].y, M[k].y};
        }
    }
    __syncthreads();

    const float* xrb = xr + (size_t)b * DIM;
    const float* xib = xi + (size_t)b * DIM;

    #define GMP(li, q) (&gmp[((li) * NQ + (q)) * 8])

    // ---- P0 (A0): global gather + rot0 on q0..q2 (reg) and q8..q13 (lane) ----
    #pragma unroll 1
    for (uint32_t sl = 0; sl < 2; ++sl) {
        const uint32_t t = tid + sl * BLK;   // bits b0..b10
        v2f v[8];
        #pragma unroll
        for (int r = 0; r < 8; ++r) {
            uint32_t i = t | ((uint32_t)r << 11);
            v[r] = v2f{xrb[i], xib[i]};
        }
        rot8<2>(v, GMP(0,0)); rot8<1>(v, GMP(0,1)); rot8<0>(v, GMP(0,2));
        rotL<1 >(v, GMP(0,13), lane); rotL<2 >(v, GMP(0,12), lane);
        rotL<4 >(v, GMP(0,11), lane); rotL<8 >(v, GMP(0,10), lane);
        rotL<16>(v, GMP(0,9),  lane); rotL<32>(v, GMP(0,8),  lane);
        cnotRR<2,1>(v);   // CNOT(0,1)
        cnotRR<1,0>(v);   // CNOT(1,2)
        const uint32_t sb = slotf2(t);
        #pragma unroll
        for (int r = 0; r < 8; ++r) s[sb ^ slotf2((uint32_t)r << 11)] = v[r];
    }
    __syncthreads();

    #define PASS_M(...)                                                         \
        _Pragma("unroll 1")                                                     \
        for (uint32_t sl = 0; sl < 2; ++sl) {                                   \
            const uint32_t base = (lane << 3) | ((tid >> 6) & 7u)               \
                                | (((tid >> 9) & 1u) << 12) | (sl << 13);       \
            const uint32_t sb = slotf2(base);                                   \
            v2f v[8];                                                           \
            _Pragma("unroll")                                                   \
            for (int r = 0; r < 8; ++r) v[r] = s[sb ^ slotf2((uint32_t)r<<9)];  \
            __VA_ARGS__                                                         \
            _Pragma("unroll")                                                   \
            for (int r = 0; r < 8; ++r) s[sb ^ slotf2((uint32_t)r<<9)] = v[r];  \
        }                                                                       \
        __syncthreads();

    #define PASS_B(...)                                                         \
        _Pragma("unroll 1")                                                     \
        for (uint32_t sl = 0; sl < 2; ++sl) {                                   \
            const uint32_t base = (lane & 3u) | (((lane >> 2) & 1u) << 5)       \
                                | (((lane >> 3) & 7u) << 11)                    \
                                | (((tid >> 6) & 15u) << 6) | (sl << 10);       \
            const uint32_t sb = slotf2(base);                                   \
            v2f v[8];                                                           \
            _Pragma("unroll")                                                   \
            for (int r = 0; r < 8; ++r) v[r] = s[sb ^ slotf2((uint32_t)r<<2)];  \
            __VA_ARGS__                                                         \
            _Pragma("unroll")                                                   \
            for (int r = 0; r < 8; ++r) s[sb ^ slotf2((uint32_t)r<<2)] = v[r];  \
        }                                                                       \
        __syncthreads();

    // M-pass body for layer li: rot q3,q4 (reg r1,r0), q5,q6,q7 (lane 32,16,8);
    // CNOT(2,3)(r2,r1) (3,4)(r1,r0) (4,5)(r0,l32) (5,6)(32,16) (6,7)(16,8)
    // (7,8)(8,4) (8,9)(4,2)
    #define MID(li)                                                             \
        rot8<1>(v, GMP(li,3)); rot8<0>(v, GMP(li,4));                           \
        rotL<32>(v, GMP(li,5), lane); rotL<16>(v, GMP(li,6), lane);             \
        rotL<8 >(v, GMP(li,7), lane);                                           \
        cnotRR<2,1>(v); cnotRR<1,0>(v); cnotRL<0,32>(v);                        \
        cnotLL<32,16>(v, lane); cnotLL<16,8>(v, lane);                          \
        cnotLL<8,4>(v, lane); cnotLL<4,2>(v, lane);

    // B-pass body: tail CNOTs of layer li then rotations of layer n=li+1 on
    // q9,q10,q11 (reg r2,r1,r0), q12(l2),q13(l1),q0(l32),q1(l16),q2(l8),q8(l4)
    #define TAILROT(n)                                                          \
        cnotRR<2,1>(v); cnotRR<1,0>(v); cnotRL<0,2>(v);                         \
        cnotLL<2,1>(v, lane); cnotLL<1,32>(v, lane);                            \
        rot8<2>(v, GMP(n,9)); rot8<1>(v, GMP(n,10)); rot8<0>(v, GMP(n,11));     \
        rotL<2 >(v, GMP(n,12), lane); rotL<1 >(v, GMP(n,13), lane);             \
        rotL<32>(v, GMP(n,0),  lane); rotL<16>(v, GMP(n,1),  lane);             \
        rotL<8 >(v, GMP(n,2),  lane); rotL<4 >(v, GMP(n,8),  lane);

    #define HEAD cnotLL<32,16>(v, lane); cnotLL<16,8>(v, lane);  // CN(0,1),(1,2)

    PASS_M(MID(0))
    PASS_B(TAILROT(1) HEAD)
    PASS_M(MID(1))
    PASS_B(TAILROT(2) HEAD)
    PASS_M(MID(2))
    PASS_B(TAILROT(3) HEAD)
    PASS_M(MID(3))
    PASS_B(TAILROT(4))          // layer-3 tail + layer-4 rotations (no ring)

    // ---- P9 (M): layer-4 rot q3..q7 + fused <Z_0>; sign = b13 = slab ----
    float local = 0.f;
    #pragma unroll 1
    for (uint32_t sl = 0; sl < 2; ++sl) {
        const uint32_t base = (lane << 3) | ((tid >> 6) & 7u)
                            | (((tid >> 9) & 1u) << 12) | (sl << 13);
        const uint32_t sb = slotf2(base);
        v2f v[8];
        #pragma unroll
        for (int r = 0; r < 8; ++r) v[r] = s[sb ^ slotf2((uint32_t)r << 9)];
        rot8<1>(v, GMP(4,3)); rot8<0>(v, GMP(4,4));
        rotL<32>(v, GMP(4,5), lane); rotL<16>(v, GMP(4,6), lane);
        rotL<8 >(v, GMP(4,7), lane);
        float acc = 0.f;
        #pragma unroll
        for (int r = 0; r < 8; ++r) { v2f p = v[r] * v[r]; acc += p.x + p.y; }
        local += sl ? -acc : acc;
    }

    #pragma unroll
    for (int off = 32; off > 0; off >>= 1) local += __shfl_down(local, off);
    const int wid = tid >> 6;
    if ((tid & 63u) == 0) red[wid] = local;
    __syncthreads();
    if (tid == 0) {
        float t = 0.f;
        #pragma unroll
        for (int k = 0; k < BLK / 64; ++k) t += red[k];
        out[b] = t;
    }
}

extern "C" void kernel_launch(void* const* d_in, const int* in_sizes, int n_in,
                              void* d_out, int out_size, void* d_ws, size_t ws_size,
                              hipStream_t stream) {
    const float* xr = (const float*)d_in[0];
    const float* xi = (const float*)d_in[1];
    const float* w  = (const float*)d_in[2];
    float* out = (float*)d_out;
    const int B = out_size;  // 512
    qsim_kernel<<<B, BLK, 0, stream>>>(xr, xi, w, out);
}

// Round 11
// 144.430 us; speedup vs baseline: 1.5081x; 1.5081x over previous
//
#include <hip/hip_runtime.h>

#define NQ   14
#define DIM  16384      // 2^14
#define BLK  1024
#define WMUL 0.6324555320336759f  // sqrt(2/5)

typedef float v2f __attribute__((ext_vector_type(2)));

struct C2 { float x, y; };  // build-time only
__device__ inline C2 cmulc(C2 a, C2 b){ return C2{a.x*b.x - a.y*b.y, a.x*b.y + a.y*b.x}; }
__device__ inline C2 caddc(C2 a, C2 b){ return C2{a.x+b.x, a.y+b.y}; }
__device__ inline void mm2(const C2* a, const C2* b, C2* o) {
    o[0] = caddc(cmulc(a[0],b[0]), cmulc(a[1],b[2]));
    o[1] = caddc(cmulc(a[0],b[1]), cmulc(a[1],b[3]));
    o[2] = caddc(cmulc(a[2],b[0]), cmulc(a[3],b[2]));
    o[3] = caddc(cmulc(a[2],b[1]), cmulc(a[3],b[3]));
}
__device__ inline void build_gate(int ty, float t, C2* g) {
    float sn, cs;
    __sincosf(0.5f * t, &sn, &cs);
    if (ty == 0) {        // rx
        g[0] = C2{cs, 0.f}; g[1] = C2{0.f, -sn};
        g[2] = C2{0.f, -sn}; g[3] = C2{cs, 0.f};
    } else if (ty == 1) { // ry
        g[0] = C2{cs, 0.f}; g[1] = C2{-sn, 0.f};
        g[2] = C2{sn, 0.f}; g[3] = C2{cs, 0.f};
    } else {              // rz
        g[0] = C2{cs, -sn}; g[1] = C2{0.f, 0.f};
        g[2] = C2{0.f, 0.f}; g[3] = C2{cs, sn};
    }
}
__device__ const int TYPES[5][3] = {
    {0,1,2},  // XYZ
    {1,2,1},  // YZY
    {2,1,0},  // ZYX
    {0,2,0},  // XZX
    {1,2,1},  // YZY
};

// bank-conflict swizzle; GF(2)-LINEAR (round-6 proven)
__device__ inline constexpr uint32_t slotf(uint32_t i){
    return i ^ (((i>>4) ^ (i>>8) ^ (i>>12)) & 15u);
}
template<int B> __device__ inline uint32_t ins0(uint32_t t){
    return ((t & ~((1u<<B)-1u)) << 1) | (t & ((1u<<B)-1u));
}
template<int B0,int B1,int B2> __device__ inline uint32_t expand3(uint32_t t){
    return ins0<B2>(ins0<B1>(ins0<B0>(t)));
}
template<int B0,int B1,int B2> __device__ inline constexpr uint32_t rmask3(int r){
    return ((r&1)?(1u<<B0):0u) | ((r&2)?(1u<<B1):0u) | ((r&4)?(1u<<B2):0u);
}

#define SBAR __builtin_amdgcn_sched_barrier(0)

// cross-lane xor exchange: masks 1,2 quad_perm DPP; 8 row_ror:8 DPP;
// 4,16 ds_swizzle; 32 shfl_xor
template<int M>
__device__ __forceinline__ v2f shflx(v2f x){
    int a = __float_as_int(x.x), b = __float_as_int(x.y);
    int ra, rb;
    if constexpr (M == 1) {
        ra = __builtin_amdgcn_mov_dpp(a, 0xB1, 0xF, 0xF, false);  // quad_perm [1,0,3,2]
        rb = __builtin_amdgcn_mov_dpp(b, 0xB1, 0xF, 0xF, false);
    } else if constexpr (M == 2) {
        ra = __builtin_amdgcn_mov_dpp(a, 0x4E, 0xF, 0xF, false);  // quad_perm [2,3,0,1]
        rb = __builtin_amdgcn_mov_dpp(b, 0x4E, 0xF, 0xF, false);
    } else if constexpr (M == 8) {
        ra = __builtin_amdgcn_mov_dpp(a, 0x128, 0xF, 0xF, false); // row_ror:8 = xor8
        rb = __builtin_amdgcn_mov_dpp(b, 0x128, 0xF, 0xF, false);
    } else if constexpr (M < 32) {
        constexpr int pat = 0x1F | (M << 10);                     // BitMode xor
        ra = __builtin_amdgcn_ds_swizzle(a, pat);
        rb = __builtin_amdgcn_ds_swizzle(b, pat);
    } else {
        ra = __shfl_xor(a, 32, 64);
        rb = __shfl_xor(b, 32, 64);
    }
    return v2f{__int_as_float(ra), __int_as_float(rb)};
}

// gate storage per gate: 8 v2f = [lo: a00,b00,a01,b01][hi: a11,b11,a10,b10]
// aXY=(Mxy.x,Mxy.x), bXY=(-Mxy.y,Mxy.y); cmul(m,a) = aXY*a + bXY*a.yx

// rotation on REG bit J
template<int J>
__device__ __forceinline__ void rot8(v2f* v, const v2f* __restrict__ g){
    const v2f a00=g[0], b00=g[1], a01=g[2], b01=g[3];
    const v2f a11=g[4], b11=g[5], a10=g[6], b10=g[7];
    #pragma unroll
    for (int r = 0; r < 8; ++r){
        if (!(r & (1 << J))) {
            v2f x0 = v[r], x1 = v[r | (1 << J)];
            v2f s0 = x0.yx, s1 = x1.yx;
            v[r]          = a00*x0 + b00*s0 + a01*x1 + b01*s1;
            v[r | (1<<J)] = a10*x0 + b10*s0 + a11*x1 + b11*s1;
        }
    }
}
// rotation on LANE bit (mask LM): coeff set selected by lane-dependent LDS addr
template<int LM>
__device__ __forceinline__ void rotL(v2f* v, const v2f* __restrict__ g, uint32_t lane){
    const v2f* gl = g + ((lane & LM) ? 4 : 0);
    const v2f c1 = gl[0], c2 = gl[1], c3 = gl[2], c4 = gl[3];
    #pragma unroll
    for (int r = 0; r < 8; ++r){
        v2f x  = v[r];
        v2f xp = shflx<LM>(x);
        v[r] = c1*x + c2*x.yx + c3*xp + c4*xp.yx;
    }
}
// CNOTs
template<int C, int T>
__device__ __forceinline__ void cnotRR(v2f* v){
    #pragma unroll
    for (int r = 0; r < 8; ++r)
        if ((r & (1<<C)) && !(r & (1<<T))) {
            v2f t = v[r]; v[r] = v[r|(1<<T)]; v[r|(1<<T)] = t;
        }
}
template<int C, int M>
__device__ __forceinline__ void cnotRL(v2f* v){
    #pragma unroll
    for (int r = 0; r < 8; ++r)
        if (r & (1<<C)) v[r] = shflx<M>(v[r]);
}
template<int CM, int T>
__device__ __forceinline__ void cnotLR(v2f* v, uint32_t lane){
    const bool c = (lane & CM) != 0;
    #pragma unroll
    for (int r = 0; r < 8; ++r)
        if (!(r & (1 << T))) {
            v2f lo = v[r], hi = v[r | (1 << T)];
            v[r]          = c ? hi : lo;
            v[r | (1<<T)] = c ? lo : hi;
        }
}
__device__ __forceinline__ v2f bperm1(v2f x, int addr){
    return v2f{__int_as_float(__builtin_amdgcn_ds_bpermute(addr, __float_as_int(x.x))),
               __int_as_float(__builtin_amdgcn_ds_bpermute(addr, __float_as_int(x.y)))};
}

// ---------------------------------------------------------------------------
// Layout: qubit q <-> bit (13-q). All windows keep lanes l0..l5 on the lowest
// non-window bits. W_A(11,12,13)/W_B(9,10,11)/W_C(7,8,9): lanes = b0..b5 ->
// q13..q8 masks 1,2,4,8,16,32. W_D(5,6,7): lanes l0..l4 = b0..b4, l5 = b8.
// Per ring layer li: P1(W_A): [CN_{li-1}(13,0)] rot q0,q1,q2 + CN(0,1),(1,2)
//  P2(W_B): rot q3,q4 + rotL q13,q12,q11 + CN(2,3),(3,4) [+rot4 q3 @li3]
//  P3(W_C): rot q5,q6 + rotL q10,q9,q8 + CN(4,5),(5,6)   [+rot4 q4,q5 @li3]
//  P4(W_D): rot q7 + CN(6,7),(7,8) + CN(8,9) RL + chain CN(9,10)..(12,13)
//           via one bpermute (src = L ^ ((L>>1)&15))      [+rot4 q6..q12 @li3]
// P_F(W_A): CN3(13,0) + rot4 q13,q0,q1,q2 + fused <Z_0> (sign bit b13 = r2)
// ---------------------------------------------------------------------------

__global__ __launch_bounds__(BLK) void qsim_kernel(
        const float* __restrict__ xr, const float* __restrict__ xi,
        const float* __restrict__ w, float* __restrict__ out) {
    __shared__ v2f s[DIM];            // 128 KiB statevector (slotf-swizzled)
    __shared__ v2f gmp[5 * NQ * 8];   // 70 gates, lo/hi coeff sets (4.4 KiB)
    __shared__ float red[BLK / 64];

    const int b    = blockIdx.x;
    const uint32_t tid  = threadIdx.x;
    const uint32_t lane = tid & 63u;
    const int csrc = (int)((lane ^ ((lane >> 1) & 15u)) << 2);  // chain bperm addr

    // ---- build fused gate matrices (threads 0..69) ----
    if (tid < 5 * NQ) {
        const int li = tid / NQ, q = tid % NQ;
        C2 M[4], G[4], T[4];
        #pragma unroll
        for (int j = 0; j < 3; ++j) {
            float t = w[3 * NQ * li + 3 * q + j] * WMUL;
            build_gate(TYPES[li][j], t, G);
            if (j == 0) { M[0]=G[0]; M[1]=G[1]; M[2]=G[2]; M[3]=G[3]; }
            else { mm2(G, M, T); M[0]=T[0]; M[1]=T[1]; M[2]=T[2]; M[3]=T[3]; }
        }
        v2f* gb = &gmp[tid * 8];
        gb[0] = v2f{ M[0].x, M[0].x}; gb[1] = v2f{-M[0].y, M[0].y};  // a00,b00
        gb[2] = v2f{ M[1].x, M[1].x}; gb[3] = v2f{-M[1].y, M[1].y};  // a01,b01
        gb[4] = v2f{ M[3].x, M[3].x}; gb[5] = v2f{-M[3].y, M[3].y};  // a11,b11
        gb[6] = v2f{ M[2].x, M[2].x}; gb[7] = v2f{-M[2].y, M[2].y};  // a10,b10
    }
    __syncthreads();

    const float* xrb = xr + (size_t)b * DIM;
    const float* xib = xi + (size_t)b * DIM;

    #define GMP(li, q) (&gmp[((li) * NQ + (q)) * 8])

    #define PASS(B0, B1, B2, ...)                                                  \
        _Pragma("unroll 1")                                                        \
        for (uint32_t sl = 0; sl < 2; ++sl) {                                      \
            const uint32_t t  = tid + sl * BLK;                                    \
            const uint32_t sb = slotf(expand3<B0,B1,B2>(t));                       \
            v2f v[8];                                                              \
            _Pragma("unroll")                                                      \
            for (int r = 0; r < 8; ++r)                                            \
                v[r] = s[sb ^ slotf(rmask3<B0,B1,B2>(r))];                         \
            __VA_ARGS__                                                            \
            _Pragma("unroll")                                                      \
            for (int r = 0; r < 8; ++r)                                            \
                s[sb ^ slotf(rmask3<B0,B1,B2>(r))] = v[r];                         \
        }                                                                          \
        __syncthreads();

    #define CHAIN { _Pragma("unroll") for (int r = 0; r < 8; ++r) v[r] = bperm1(v[r], csrc); }

    #pragma unroll 1
    for (int li = 0; li < 4; ++li) {
        // ---- P1 (W_A): [CN_{li-1}(13,0)] rot q0,q1,q2; CN(0,1),(1,2) ----
        #pragma unroll 1
        for (uint32_t sl = 0; sl < 2; ++sl) {
            const uint32_t t = tid + sl * BLK;
            v2f v[8];
            if (li == 0) {
                #pragma unroll
                for (int r = 0; r < 8; ++r) {
                    uint32_t i = t | ((uint32_t)r << 11);   // expand3<11,12,13>(t)=t
                    v[r] = v2f{xrb[i], xib[i]};
                }
            } else {
                const uint32_t sb = slotf(expand3<11,12,13>(t));
                #pragma unroll
                for (int r = 0; r < 8; ++r)
                    v[r] = s[sb ^ slotf(rmask3<11,12,13>(r))];
                cnotLR<1,2>(v, lane);                     // CN_{li-1}(13,0)
            }
            rot8<2>(v, GMP(li,0)); rot8<1>(v, GMP(li,1)); SBAR;
            rot8<0>(v, GMP(li,2));
            cnotRR<2,1>(v); cnotRR<1,0>(v);               // CN(0,1),(1,2)
            const uint32_t sb = slotf(expand3<11,12,13>(t));
            #pragma unroll
            for (int r = 0; r < 8; ++r)
                s[sb ^ slotf(rmask3<11,12,13>(r))] = v[r];
        }
        __syncthreads();

        // ---- P2 (W_B): rot q3(r1),q4(r0); rotL q13,q12,q11; CN(2,3),(3,4) ----
        PASS(9,10,11,
            rot8<1>(v, GMP(li,3)); rot8<0>(v, GMP(li,4)); SBAR;
            rotL<1>(v, GMP(li,13), lane); rotL<2>(v, GMP(li,12), lane); SBAR;
            rotL<4>(v, GMP(li,11), lane);
            cnotRR<2,1>(v); cnotRR<1,0>(v);               // CN(2,3),(3,4)
            if (li == 3) { SBAR; rot8<1>(v, GMP(4,3)); }  // rot4 q3
        )
        // ---- P3 (W_C): rot q5(r1),q6(r0); rotL q10,q9,q8; CN(4,5),(5,6) ----
        PASS(7,8,9,
            rot8<1>(v, GMP(li,5)); rot8<0>(v, GMP(li,6)); SBAR;
            rotL<8>(v, GMP(li,10), lane); rotL<16>(v, GMP(li,9), lane); SBAR;
            rotL<32>(v, GMP(li,8), lane);
            cnotRR<2,1>(v); cnotRR<1,0>(v);               // CN(4,5),(5,6)
            if (li == 3) { SBAR; rot8<2>(v, GMP(4,4)); rot8<1>(v, GMP(4,5)); } // rot4 q4,q5
        )
        // ---- P4 (W_D): rot q7(r1); CN(6,7),(7,8) RR; CN(8,9) RL; chain ----
        PASS(5,6,7,
            rot8<1>(v, GMP(li,7));
            cnotRR<2,1>(v); cnotRR<1,0>(v);               // CN(6,7),(7,8)
            cnotRL<0,16>(v);                              // CN(8,9): ctl b5(r0), tgt b4
            CHAIN                                         // CN(9,10)..(12,13)
            if (li == 3) {
                SBAR; rot8<2>(v, GMP(4,6)); rot8<1>(v, GMP(4,7)); SBAR;
                rot8<0>(v, GMP(4,8)); rotL<16>(v, GMP(4,9), lane); SBAR;
                rotL<8>(v, GMP(4,10), lane); rotL<4>(v, GMP(4,11), lane); SBAR;
                rotL<2>(v, GMP(4,12), lane);              // rot4 q6..q12
            }
        )
    }

    // ---- P_F (W_A): CN3(13,0); rot4 q13,q0,q1,q2; fused <Z_0> ----
    float local = 0.f;
    #pragma unroll 1
    for (uint32_t sl = 0; sl < 2; ++sl) {
        const uint32_t t  = tid + sl * BLK;
        const uint32_t sb = slotf(expand3<11,12,13>(t));
        v2f v[8];
        #pragma unroll
        for (int r = 0; r < 8; ++r)
            v[r] = s[sb ^ slotf(rmask3<11,12,13>(r))];
        cnotLR<1,2>(v, lane);                             // CN3(13,0)
        rotL<1>(v, GMP(4,13), lane); SBAR;
        rot8<2>(v, GMP(4,0)); rot8<1>(v, GMP(4,1)); SBAR;
        rot8<0>(v, GMP(4,2));
        #pragma unroll
        for (int r = 0; r < 8; ++r) {
            v2f p = v[r] * v[r];
            float m = p.x + p.y;
            local += (r & 4) ? -m : m;                    // sign = b13 = r2
        }
    }

    #pragma unroll
    for (int off = 32; off > 0; off >>= 1) local += __shfl_down(local, off);
    const int wid = tid >> 6;
    if ((tid & 63u) == 0) red[wid] = local;
    __syncthreads();
    if (tid == 0) {
        float t = 0.f;
        #pragma unroll
        for (int k = 0; k < BLK / 64; ++k) t += red[k];
        out[b] = t;
    }
}

extern "C" void kernel_launch(void* const* d_in, const int* in_sizes, int n_in,
                              void* d_out, int out_size, void* d_ws, size_t ws_size,
                              hipStream_t stream) {
    const float* xr = (const float*)d_in[0];
    const float* xi = (const float*)d_in[1];
    const float* w  = (const float*)d_in[2];
    float* out = (float*)d_out;
    const int B = out_size;  // 512
    qsim_kernel<<<B, BLK, 0, stream>>>(xr, xi, w, out);
}

// Round 12
// 115.207 us; speedup vs baseline: 1.8907x; 1.2537x over previous
//
#include <hip/hip_runtime.h>
#include <hip/hip_bf16.h>

#define NQ   14
#define DIM  16384      // 2^14
#define BLK  1024
#define WMUL 0.6324555320336759f  // sqrt(2/5)

typedef float v2f __attribute__((ext_vector_type(2)));

struct C2 { float x, y; };  // build-time only
__device__ inline C2 cmulc(C2 a, C2 b){ return C2{a.x*b.x - a.y*b.y, a.x*b.y + a.y*b.x}; }
__device__ inline C2 caddc(C2 a, C2 b){ return C2{a.x+b.x, a.y+b.y}; }
__device__ inline void mm2(const C2* a, const C2* b, C2* o) {
    o[0] = caddc(cmulc(a[0],b[0]), cmulc(a[1],b[2]));
    o[1] = caddc(cmulc(a[0],b[1]), cmulc(a[1],b[3]));
    o[2] = caddc(cmulc(a[2],b[0]), cmulc(a[3],b[2]));
    o[3] = caddc(cmulc(a[2],b[1]), cmulc(a[3],b[3]));
}
__device__ inline void build_gate(int ty, float t, C2* g) {
    float sn, cs;
    __sincosf(0.5f * t, &sn, &cs);
    if (ty == 0) {        // rx
        g[0] = C2{cs, 0.f}; g[1] = C2{0.f, -sn};
        g[2] = C2{0.f, -sn}; g[3] = C2{cs, 0.f};
    } else if (ty == 1) { // ry
        g[0] = C2{cs, 0.f}; g[1] = C2{-sn, 0.f};
        g[2] = C2{sn, 0.f}; g[3] = C2{cs, 0.f};
    } else {              // rz
        g[0] = C2{cs, -sn}; g[1] = C2{0.f, 0.f};
        g[2] = C2{0.f, 0.f}; g[3] = C2{cs, sn};
    }
}
__device__ const int TYPES[5][3] = {
    {0,1,2},  // XYZ
    {1,2,1},  // YZY
    {2,1,0},  // ZYX
    {0,2,0},  // XZX
    {1,2,1},  // YZY
};

// bank-conflict swizzle; GF(2)-LINEAR: slotf(a|b) = slotf(a)^slotf(b) for disjoint a,b
__device__ inline constexpr uint32_t slotf(uint32_t i){
    return i ^ (((i>>4) ^ (i>>8) ^ (i>>12)) & 15u);
}
template<int B> __device__ inline uint32_t ins0(uint32_t t){
    return ((t & ~((1u<<B)-1u)) << 1) | (t & ((1u<<B)-1u));
}
template<int B0,int B1,int B2> __device__ inline uint32_t expand3(uint32_t t){
    return ins0<B2>(ins0<B1>(ins0<B0>(t)));
}
template<int B0,int B1,int B2> __device__ inline constexpr uint32_t rmask3(int r){
    return ((r&1)?(1u<<B0):0u) | ((r&2)?(1u<<B1):0u) | ((r&4)?(1u<<B2):0u);
}

// packed rotation on local bit J. g = 8 v2f: {mxx, msw} per coeff (00,01,10,11),
// mxx = (m.x,m.x), msw = (-m.y,m.y): cmul(m,a) = mxx*a + msw*a.yx
template<int J>
__device__ inline void rot8(v2f* v, const v2f* __restrict__ g){
    const v2f a00=g[0], b00=g[1], a01=g[2], b01=g[3];
    const v2f a10=g[4], b10=g[5], a11=g[6], b11=g[7];
    #pragma unroll
    for (int r = 0; r < 8; ++r){
        if (!(r & (1 << J))) {
            v2f x0 = v[r], x1 = v[r | (1 << J)];
            v2f s0 = x0.yx, s1 = x1.yx;
            v2f y0 = a00*x0 + b00*s0 + a01*x1 + b01*s1;
            v2f y1 = a10*x0 + b10*s0 + a11*x1 + b11*s1;
            v[r] = y0; v[r | (1<<J)] = y1;
        }
    }
}
// CNOT: control local bit C, target local bit T (register renaming, ~free)
template<int C, int T>
__device__ inline void cnot8(v2f* v){
    #pragma unroll
    for (int r = 0; r < 8; ++r){
        if ((r & (1 << C)) && !(r & (1 << T))) {
            v2f tt = v[r]; v[r] = v[r | (1 << T)]; v[r | (1 << T)] = tt;
        }
    }
}

__global__ __launch_bounds__(BLK) void qsim_kernel(
        const float* __restrict__ xr, const float* __restrict__ xi,
        const float* __restrict__ w, float* __restrict__ out) {
    __shared__ v2f s[DIM];            // 128 KiB statevector (swizzled layout)
    __shared__ v2f gmp[5 * NQ * 8];   // 70 gates, packed-friendly form (4.4 KiB)
    __shared__ float meas[4];         // absorbed-L5 observable: alpha, beta, p, q
    __shared__ float red[BLK / 64];

    const int b   = blockIdx.x;
    const uint32_t tid = threadIdx.x;

    // ---- build fused gate matrices (threads 0..69), store packed form ----
    if (tid < 5 * NQ) {
        const int li = tid / NQ, q = tid % NQ;
        C2 M[4], G[4], T[4];
        #pragma unroll
        for (int j = 0; j < 3; ++j) {
            float t = w[3 * NQ * li + 3 * q + j] * WMUL;
            build_gate(TYPES[li][j], t, G);
            if (j == 0) { M[0]=G[0]; M[1]=G[1]; M[2]=G[2]; M[3]=G[3]; }
            else { mm2(G, M, T); M[0]=T[0]; M[1]=T[1]; M[2]=T[2]; M[3]=T[3]; }
        }
        #pragma unroll
        for (int k = 0; k < 4; ++k) {
            gmp[tid * 8 + k * 2 + 0] = v2f{ M[k].x, M[k].x};
            gmp[tid * 8 + k * 2 + 1] = v2f{-M[k].y, M[k].y};
        }
        // absorbed observable M1 = M† Z M for the layer-5 qubit-0 rotation:
        // M1_00 = |M00|^2-|M10|^2 ; M1_11 = |M01|^2-|M11|^2 ;
        // M1_01 = conj(M00)M01 - conj(M10)M11 = p + i q
        if (tid == 4 * NQ + 0) {
            meas[0] = M[0].x*M[0].x + M[0].y*M[0].y - (M[2].x*M[2].x + M[2].y*M[2].y);
            meas[1] = M[1].x*M[1].x + M[1].y*M[1].y - (M[3].x*M[3].x + M[3].y*M[3].y);
            meas[2] = (M[0].x*M[1].x + M[0].y*M[1].y) - (M[2].x*M[3].x + M[2].y*M[3].y);
            meas[3] = (M[0].x*M[1].y - M[0].y*M[1].x) - (M[2].x*M[3].y - M[2].y*M[3].x);
        }
    }
    __syncthreads();

    const float* xrb = xr + (size_t)b * DIM;
    const float* xib = xi + (size_t)b * DIM;

    // qubit q <-> bit (13-q).
    #define GMP(li, q) (&gmp[((li) * NQ + (q)) * 8])

    // One pass: 2 sequential slabs (live state = v2f v[8] = 16 VGPRs).
    #define PASS(B0, B1, B2, ...)                                                  \
        _Pragma("unroll 1")                                                        \
        for (uint32_t sl = 0; sl < 2; ++sl) {                                      \
            const uint32_t t  = tid + sl * BLK;                                    \
            const uint32_t sb = slotf(expand3<B0,B1,B2>(t));                       \
            v2f v[8];                                                              \
            _Pragma("unroll")                                                      \
            for (int r = 0; r < 8; ++r)                                            \
                v[r] = s[sb ^ slotf(rmask3<B0,B1,B2>(r))];                         \
            __VA_ARGS__                                                            \
            _Pragma("unroll")                                                      \
            for (int r = 0; r < 8; ++r)                                            \
                s[sb ^ slotf(rmask3<B0,B1,B2>(r))] = v[r];                         \
        }                                                                          \
        __syncthreads();

    float local = 0.f;

    // ---- 4 ring layers, 7 windows each; L5 is absorbed into meas[] ----
    #pragma unroll 1
    for (int li = 0; li < 4; ++li) {
        // W1 bits{11,12,13}: L2=q0, L1=q1, L0=q2: rot q0,q1,q2 + CN(0,1),(1,2)
        #pragma unroll 1
        for (uint32_t sl = 0; sl < 2; ++sl) {
            const uint32_t t = tid + sl * BLK;
            v2f v[8];
            if (li == 0) {
                #pragma unroll
                for (int r = 0; r < 8; ++r) {
                    uint32_t i = t | ((uint32_t)r << 11);   // expand3<11,12,13>(t)=t
                    v[r] = v2f{xrb[i], xib[i]};
                }
            } else {
                const uint32_t sb = slotf(expand3<11,12,13>(t));
                #pragma unroll
                for (int r = 0; r < 8; ++r)
                    v[r] = s[sb ^ slotf(rmask3<11,12,13>(r))];
            }
            rot8<2>(v, GMP(li,0)); rot8<1>(v, GMP(li,1)); rot8<0>(v, GMP(li,2));
            cnot8<2,1>(v); cnot8<1,0>(v);
            const uint32_t sb = slotf(expand3<11,12,13>(t));
            #pragma unroll
            for (int r = 0; r < 8; ++r)
                s[sb ^ slotf(rmask3<11,12,13>(r))] = v[r];
        }
        __syncthreads();

        // W2..W6: sliding 3-bit windows, rot 2 + CNOT 2 each
        PASS(9,10,11, rot8<1>(v, GMP(li,3));  rot8<0>(v, GMP(li,4));  cnot8<2,1>(v); cnot8<1,0>(v);)
        PASS(7,8,9,   rot8<1>(v, GMP(li,5));  rot8<0>(v, GMP(li,6));  cnot8<2,1>(v); cnot8<1,0>(v);)
        PASS(5,6,7,   rot8<1>(v, GMP(li,7));  rot8<0>(v, GMP(li,8));  cnot8<2,1>(v); cnot8<1,0>(v);)
        PASS(3,4,5,   rot8<1>(v, GMP(li,9));  rot8<0>(v, GMP(li,10)); cnot8<2,1>(v); cnot8<1,0>(v);)
        PASS(1,2,3,   rot8<1>(v, GMP(li,11)); rot8<0>(v, GMP(li,12)); cnot8<2,1>(v); cnot8<1,0>(v);)

        // W7 bits{0,1,13}: L0=q13, L1=q12, L2=q0: rot q13 + CN(12,13),(13,0).
        // At li==3 the state evolution is COMPLETE after these CNOTs (L5 is
        // absorbed) -> fuse the M1 quadratic form on b13 pairs (r, r|4), no scatter.
        #pragma unroll 1
        for (uint32_t sl = 0; sl < 2; ++sl) {
            const uint32_t t  = tid + sl * BLK;
            const uint32_t sb = slotf(expand3<0,1,13>(t));
            v2f v[8];
            #pragma unroll
            for (int r = 0; r < 8; ++r)
                v[r] = s[sb ^ slotf(rmask3<0,1,13>(r))];
            rot8<0>(v, GMP(li,13));
            cnot8<1,0>(v); cnot8<0,2>(v);
            if (li < 3) {
                #pragma unroll
                for (int r = 0; r < 8; ++r)
                    s[sb ^ slotf(rmask3<0,1,13>(r))] = v[r];
            } else {
                const float mA = meas[0], mB = meas[1], mP = meas[2], mQ = meas[3];
                #pragma unroll
                for (int r = 0; r < 4; ++r) {
                    v2f a0 = v[r], a1 = v[r | 4];         // b13=0 / b13=1
                    float n0 = a0.x*a0.x + a0.y*a0.y;
                    float n1 = a1.x*a1.x + a1.y*a1.y;
                    float u  = a0.x*a1.x + a0.y*a1.y;     // Re(conj(a0) a1)
                    float vv = a0.x*a1.y - a0.y*a1.x;     // Im(conj(a0) a1)
                    local += mA*n0 + mB*n1 + 2.f*(mP*u - mQ*vv);
                }
            }
        }
        if (li < 3) __syncthreads();
    }

    #pragma unroll
    for (int off = 32; off > 0; off >>= 1) local += __shfl_down(local, off);
    const int lane = tid & 63, wid = tid >> 6;
    if (lane == 0) red[wid] = local;
    __syncthreads();
    if (tid == 0) {
        float t = 0.f;
        #pragma unroll
        for (int k = 0; k < BLK / 64; ++k) t += red[k];
        out[b] = t;
    }
}

extern "C" void kernel_launch(void* const* d_in, const int* in_sizes, int n_in,
                              void* d_out, int out_size, void* d_ws, size_t ws_size,
                              hipStream_t stream) {
    const float* xr = (const float*)d_in[0];
    const float* xi = (const float*)d_in[1];
    const float* w  = (const float*)d_in[2];
    float* out = (float*)d_out;
    const int B = out_size;  // 512
    qsim_kernel<<<B, BLK, 0, stream>>>(xr, xi, w, out);
}

// Round 13
// 114.097 us; speedup vs baseline: 1.9091x; 1.0097x over previous
//
#include <hip/hip_runtime.h>
#include <hip/hip_bf16.h>

#define NQ   14
#define DIM  16384      // 2^14
#define BLK  1024
#define WMUL 0.6324555320336759f  // sqrt(2/5)

typedef float v2f __attribute__((ext_vector_type(2)));

struct C2 { float x, y; };  // build-time only
__device__ inline C2 cmulc(C2 a, C2 b){ return C2{a.x*b.x - a.y*b.y, a.x*b.y + a.y*b.x}; }
__device__ inline C2 caddc(C2 a, C2 b){ return C2{a.x+b.x, a.y+b.y}; }
__device__ inline void mm2(const C2* a, const C2* b, C2* o) {
    o[0] = caddc(cmulc(a[0],b[0]), cmulc(a[1],b[2]));
    o[1] = caddc(cmulc(a[0],b[1]), cmulc(a[1],b[3]));
    o[2] = caddc(cmulc(a[2],b[0]), cmulc(a[3],b[2]));
    o[3] = caddc(cmulc(a[2],b[1]), cmulc(a[3],b[3]));
}
__device__ inline void build_gate(int ty, float t, C2* g) {
    float sn, cs;
    __sincosf(0.5f * t, &sn, &cs);
    if (ty == 0) {        // rx
        g[0] = C2{cs, 0.f}; g[1] = C2{0.f, -sn};
        g[2] = C2{0.f, -sn}; g[3] = C2{cs, 0.f};
    } else if (ty == 1) { // ry
        g[0] = C2{cs, 0.f}; g[1] = C2{-sn, 0.f};
        g[2] = C2{sn, 0.f}; g[3] = C2{cs, 0.f};
    } else {              // rz
        g[0] = C2{cs, -sn}; g[1] = C2{0.f, 0.f};
        g[2] = C2{0.f, 0.f}; g[3] = C2{cs, sn};
    }
}
__device__ const int TYPES[5][3] = {
    {0,1,2},  // XYZ
    {1,2,1},  // YZY
    {2,1,0},  // ZYX
    {0,2,0},  // XZX
    {1,2,1},  // YZY
};

// bank-conflict swizzle; GF(2)-LINEAR: slotf(a|b) = slotf(a)^slotf(b) for disjoint a,b
__device__ inline constexpr uint32_t slotf(uint32_t i){
    return i ^ (((i>>4) ^ (i>>8) ^ (i>>12)) & 15u);
}
template<int B> __device__ inline uint32_t ins0(uint32_t t){
    return ((t & ~((1u<<B)-1u)) << 1) | (t & ((1u<<B)-1u));
}
template<int B0,int B1,int B2> __device__ inline uint32_t expand3(uint32_t t){
    return ins0<B2>(ins0<B1>(ins0<B0>(t)));
}
template<int B0,int B1,int B2> __device__ inline constexpr uint32_t rmask3(int r){
    return ((r&1)?(1u<<B0):0u) | ((r&2)?(1u<<B1):0u) | ((r&4)?(1u<<B2):0u);
}

// packed rotation on local bit J. g = 8 v2f: {mxx, msw} per coeff (00,01,10,11),
// mxx = (m.x,m.x), msw = (-m.y,m.y): cmul(m,a) = mxx*a + msw*a.yx
template<int J>
__device__ inline void rot8(v2f* v, const v2f* __restrict__ g){
    const v2f a00=g[0], b00=g[1], a01=g[2], b01=g[3];
    const v2f a10=g[4], b10=g[5], a11=g[6], b11=g[7];
    #pragma unroll
    for (int r = 0; r < 8; ++r){
        if (!(r & (1 << J))) {
            v2f x0 = v[r], x1 = v[r | (1 << J)];
            v2f s0 = x0.yx, s1 = x1.yx;
            v2f y0 = a00*x0 + b00*s0 + a01*x1 + b01*s1;
            v2f y1 = a10*x0 + b10*s0 + a11*x1 + b11*s1;
            v[r] = y0; v[r | (1<<J)] = y1;
        }
    }
}
// CNOT both-in-reg: control bit C, target bit T (register renaming, free)
template<int C, int T>
__device__ inline void cnot8(v2f* v){
    #pragma unroll
    for (int r = 0; r < 8; ++r){
        if ((r & (1 << C)) && !(r & (1 << T))) {
            v2f tt = v[r]; v[r] = v[r | (1 << T)]; v[r | (1 << T)] = tt;
        }
    }
}
// CNOT with control = thread-index bit (wave-uniform per thread), target reg bit T:
// conditional pair swap, pure v_cndmask — no exchange, no LDS.
template<int T>
__device__ inline void cnotSel(v2f* v, bool c){
    #pragma unroll
    for (int r = 0; r < 8; ++r){
        if (!(r & (1 << T))) {
            v2f lo = v[r], hi = v[r | (1 << T)];
            v[r]          = c ? hi : lo;
            v[r | (1<<T)] = c ? lo : hi;
        }
    }
}

__global__ __launch_bounds__(BLK) void qsim_kernel(
        const float* __restrict__ xr, const float* __restrict__ xi,
        const float* __restrict__ w, float* __restrict__ out) {
    __shared__ v2f s[DIM];            // 128 KiB statevector (swizzled layout)
    __shared__ v2f gmp[5 * NQ * 8];   // 70 gates, packed-friendly form (4.4 KiB)
    __shared__ float meas[4];         // absorbed-L5 observable: alpha, beta, p, q
    __shared__ float red[BLK / 64];

    const int b   = blockIdx.x;
    const uint32_t tid = threadIdx.x;

    // ---- build fused gate matrices (threads 0..69), store packed form ----
    if (tid < 5 * NQ) {
        const int li = tid / NQ, q = tid % NQ;
        C2 M[4], G[4], T[4];
        #pragma unroll
        for (int j = 0; j < 3; ++j) {
            float t = w[3 * NQ * li + 3 * q + j] * WMUL;
            build_gate(TYPES[li][j], t, G);
            if (j == 0) { M[0]=G[0]; M[1]=G[1]; M[2]=G[2]; M[3]=G[3]; }
            else { mm2(G, M, T); M[0]=T[0]; M[1]=T[1]; M[2]=T[2]; M[3]=T[3]; }
        }
        #pragma unroll
        for (int k = 0; k < 4; ++k) {
            gmp[tid * 8 + k * 2 + 0] = v2f{ M[k].x, M[k].x};
            gmp[tid * 8 + k * 2 + 1] = v2f{-M[k].y, M[k].y};
        }
        // absorbed observable M1 = M† Z M for the layer-5 qubit-0 rotation
        if (tid == 4 * NQ + 0) {
            meas[0] = M[0].x*M[0].x + M[0].y*M[0].y - (M[2].x*M[2].x + M[2].y*M[2].y);
            meas[1] = M[1].x*M[1].x + M[1].y*M[1].y - (M[3].x*M[3].x + M[3].y*M[3].y);
            meas[2] = (M[0].x*M[1].x + M[0].y*M[1].y) - (M[2].x*M[3].x + M[2].y*M[3].y);
            meas[3] = (M[0].x*M[1].y - M[0].y*M[1].x) - (M[2].x*M[3].y - M[2].y*M[3].x);
        }
    }
    __syncthreads();

    const float* xrb = xr + (size_t)b * DIM;
    const float* xib = xi + (size_t)b * DIM;

    // qubit q <-> bit (13-q).
    #define GMP(li, q) (&gmp[((li) * NQ + (q)) * 8])

    // One pass: 2 sequential slabs (live state = v2f v[8] = 16 VGPRs).
    #define PASS(B0, B1, B2, ...)                                                  \
        _Pragma("unroll 1")                                                        \
        for (uint32_t sl = 0; sl < 2; ++sl) {                                      \
            const uint32_t t  = tid + sl * BLK;                                    \
            const uint32_t sb = slotf(expand3<B0,B1,B2>(t));                       \
            v2f v[8];                                                              \
            _Pragma("unroll")                                                      \
            for (int r = 0; r < 8; ++r)                                            \
                v[r] = s[sb ^ slotf(rmask3<B0,B1,B2>(r))];                         \
            __VA_ARGS__                                                            \
            _Pragma("unroll")                                                      \
            for (int r = 0; r < 8; ++r)                                            \
                s[sb ^ slotf(rmask3<B0,B1,B2>(r))] = v[r];                         \
        }                                                                          \
        __syncthreads();

    float local = 0.f;

    // ---- 4 ring layers, 5 non-overlapping windows each; L5 absorbed in meas[] ----
    // A(11,12,13): rot q0,q1,q2 + CN(0,1),(1,2)
    // B(8,9,10):   rot q3,q4,q5 + CN(2,3)[sel ctl=b11=t8] + CN(3,4),(4,5)
    // C(5,6,7):    rot q6,q7,q8 + CN(5,6)[sel ctl=b8=t5]  + CN(6,7),(7,8)
    // D(2,3,4):    rot q9,q10,q11 + CN(8,9)[sel ctl=b5=t2] + CN(9,10),(10,11)
    // E(0,1,13):   rot q12,q13 + CN(11,12)[sel ctl=b2=t0] + CN(12,13),(13,0)
    //              (li==3: fuse M1 quadratic form on b13 = L2 pairs, no scatter)
    #pragma unroll 1
    for (int li = 0; li < 4; ++li) {
        // ---- A (11,12,13) ----
        #pragma unroll 1
        for (uint32_t sl = 0; sl < 2; ++sl) {
            const uint32_t t = tid + sl * BLK;
            v2f v[8];
            if (li == 0) {
                #pragma unroll
                for (int r = 0; r < 8; ++r) {
                    uint32_t i = t | ((uint32_t)r << 11);   // expand3<11,12,13>(t)=t
                    v[r] = v2f{xrb[i], xib[i]};
                }
            } else {
                const uint32_t sb = slotf(expand3<11,12,13>(t));
                #pragma unroll
                for (int r = 0; r < 8; ++r)
                    v[r] = s[sb ^ slotf(rmask3<11,12,13>(r))];
            }
            rot8<2>(v, GMP(li,0)); rot8<1>(v, GMP(li,1)); rot8<0>(v, GMP(li,2));
            cnot8<2,1>(v); cnot8<1,0>(v);                  // CN(0,1),(1,2)
            const uint32_t sb = slotf(expand3<11,12,13>(t));
            #pragma unroll
            for (int r = 0; r < 8; ++r)
                s[sb ^ slotf(rmask3<11,12,13>(r))] = v[r];
        }
        __syncthreads();

        // ---- B (8,9,10): rot q3(b10),q4(b9),q5(b8) ----
        PASS(8,9,10,
            rot8<2>(v, GMP(li,3)); rot8<1>(v, GMP(li,4)); rot8<0>(v, GMP(li,5));
            cnotSel<2>(v, (t >> 8) & 1u);                  // CN(2,3): ctl q2=b11
            cnot8<2,1>(v); cnot8<1,0>(v);                  // CN(3,4),(4,5)
        )
        // ---- C (5,6,7): rot q6(b7),q7(b6),q8(b5) ----
        PASS(5,6,7,
            rot8<2>(v, GMP(li,6)); rot8<1>(v, GMP(li,7)); rot8<0>(v, GMP(li,8));
            cnotSel<2>(v, (t >> 5) & 1u);                  // CN(5,6): ctl q5=b8
            cnot8<2,1>(v); cnot8<1,0>(v);                  // CN(6,7),(7,8)
        )
        // ---- D (2,3,4): rot q9(b4),q10(b3),q11(b2) ----
        PASS(2,3,4,
            rot8<2>(v, GMP(li,9)); rot8<1>(v, GMP(li,10)); rot8<0>(v, GMP(li,11));
            cnotSel<2>(v, (t >> 2) & 1u);                  // CN(8,9): ctl q8=b5
            cnot8<2,1>(v); cnot8<1,0>(v);                  // CN(9,10),(10,11)
        )
        // ---- E (0,1,13): rot q12(b1=L1),q13(b0=L0) ----
        #pragma unroll 1
        for (uint32_t sl = 0; sl < 2; ++sl) {
            const uint32_t t  = tid + sl * BLK;
            const uint32_t sb = slotf(expand3<0,1,13>(t));
            v2f v[8];
            #pragma unroll
            for (int r = 0; r < 8; ++r)
                v[r] = s[sb ^ slotf(rmask3<0,1,13>(r))];
            rot8<1>(v, GMP(li,12)); rot8<0>(v, GMP(li,13));
            cnotSel<1>(v, t & 1u);                         // CN(11,12): ctl q11=b2
            cnot8<1,0>(v);                                 // CN(12,13)
            cnot8<0,2>(v);                                 // CN(13,0)
            if (li < 3) {
                #pragma unroll
                for (int r = 0; r < 8; ++r)
                    s[sb ^ slotf(rmask3<0,1,13>(r))] = v[r];
            } else {
                const float mA = meas[0], mB = meas[1], mP = meas[2], mQ = meas[3];
                #pragma unroll
                for (int r = 0; r < 4; ++r) {
                    v2f a0 = v[r], a1 = v[r | 4];          // b13=0 / b13=1
                    float n0 = a0.x*a0.x + a0.y*a0.y;
                    float n1 = a1.x*a1.x + a1.y*a1.y;
                    float u  = a0.x*a1.x + a0.y*a1.y;      // Re(conj(a0) a1)
                    float vv = a0.x*a1.y - a0.y*a1.x;      // Im(conj(a0) a1)
                    local += mA*n0 + mB*n1 + 2.f*(mP*u - mQ*vv);
                }
            }
        }
        if (li < 3) __syncthreads();
    }

    #pragma unroll
    for (int off = 32; off > 0; off >>= 1) local += __shfl_down(local, off);
    const int lane = tid & 63, wid = tid >> 6;
    if (lane == 0) red[wid] = local;
    __syncthreads();
    if (tid == 0) {
        float t = 0.f;
        #pragma unroll
        for (int k = 0; k < BLK / 64; ++k) t += red[k];
        out[b] = t;
    }
}

extern "C" void kernel_launch(void* const* d_in, const int* in_sizes, int n_in,
                              void* d_out, int out_size, void* d_ws, size_t ws_size,
                              hipStream_t stream) {
    const float* xr = (const float*)d_in[0];
    const float* xi = (const float*)d_in[1];
    const float* w  = (const float*)d_in[2];
    float* out = (float*)d_out;
    const int B = out_size;  // 512
    qsim_kernel<<<B, BLK, 0, stream>>>(xr, xi, w, out);
}